// Round 2
// baseline (14620.645 us; speedup 1.0000x reference)
//
#include <hip/hip_runtime.h>

// LIF benchmark: xs = einsum('tbf,gf->tbg', S, W)  (fp32 GEMM, A=S [T*B,512], B=W [512,512], NT)
// then sequential scan over T with per-neuron (v,i) state and heaviside threshold.
// Outputs: [z_final, z_final, v_final, i_final], each [128,512] fp32.
//
// R1: GEMM double-buffered (single barrier/iter), staging remap kills 4-way
// store conflicts; scan gets a depth-16 prefetch ring buffer (was latency-bound).
// Inner-loop arithmetic is expression-identical to the R0 version (absmax 0.0).

#define T_DIM 1024
#define B_DIM 128
#define F_DIM 512
#define NB (B_DIM * F_DIM)  // 65536 neurons

// ---------------- GEMM: C[m][n] = sum_k A[m][k] * W[n][k] ----------------
// Tile 128x128, 256 threads, 8x8 micro-tile, KC=16, double-buffered LDS.
#define TM 128
#define TN 128
#define KC 16
#define LDSS 132  // padded leading dim (floats); store banks = (16b'+4c+r)%32 -> 2-way (free)

__global__ __launch_bounds__(256, 4)
void gemm_kernel(const float* __restrict__ A, const float* __restrict__ W,
                 float* __restrict__ C) {
    __shared__ float As[2][KC * LDSS];  // [k][m]
    __shared__ float Bs[2][KC * LDSS];  // [k][n]
    const int tid = threadIdx.x;
    const int m0 = blockIdx.x * TM;
    const int n0 = blockIdx.y * TN;
    const int tn = (tid & 15) * 4;   // + {0..3} and +64
    const int tm = (tid >> 4) * 4;
    const int srow = tid >> 2;       // staging row 0..63 (+64p)
    const int sk = (tid & 3) * 4;    // staging k 0,4,8,12

    const float* Ag = A + (size_t)(m0 + srow) * F_DIM + sk;
    const float* Wg = W + (size_t)(n0 + srow) * F_DIM + sk;

    float acc[8][8];
    #pragma unroll
    for (int i = 0; i < 8; ++i)
        #pragma unroll
        for (int j = 0; j < 8; ++j) acc[i][j] = 0.f;

    float4 av0, av1, bv0, bv1;
    // preload tile 0 into regs, store to buffer 0
    av0 = *(const float4*)(Ag);
    av1 = *(const float4*)(Ag + (size_t)64 * F_DIM);
    bv0 = *(const float4*)(Wg);
    bv1 = *(const float4*)(Wg + (size_t)64 * F_DIM);
    {
        float* as = &As[0][0];
        float* bs = &Bs[0][0];
        as[(sk + 0) * LDSS + srow] = av0.x;  as[(sk + 1) * LDSS + srow] = av0.y;
        as[(sk + 2) * LDSS + srow] = av0.z;  as[(sk + 3) * LDSS + srow] = av0.w;
        as[(sk + 0) * LDSS + srow + 64] = av1.x;  as[(sk + 1) * LDSS + srow + 64] = av1.y;
        as[(sk + 2) * LDSS + srow + 64] = av1.z;  as[(sk + 3) * LDSS + srow + 64] = av1.w;
        bs[(sk + 0) * LDSS + srow] = bv0.x;  bs[(sk + 1) * LDSS + srow] = bv0.y;
        bs[(sk + 2) * LDSS + srow] = bv0.z;  bs[(sk + 3) * LDSS + srow] = bv0.w;
        bs[(sk + 0) * LDSS + srow + 64] = bv1.x;  bs[(sk + 1) * LDSS + srow + 64] = bv1.y;
        bs[(sk + 2) * LDSS + srow + 64] = bv1.z;  bs[(sk + 3) * LDSS + srow + 64] = bv1.w;
    }
    __syncthreads();

    int p = 0;
    for (int k0 = 0; k0 < F_DIM; k0 += KC) {
        const bool has_next = (k0 + KC < F_DIM);
        if (has_next) {
            const float* Agp = Ag + k0 + KC;
            const float* Wgp = Wg + k0 + KC;
            av0 = *(const float4*)(Agp);
            av1 = *(const float4*)(Agp + (size_t)64 * F_DIM);
            bv0 = *(const float4*)(Wgp);
            bv1 = *(const float4*)(Wgp + (size_t)64 * F_DIM);
        }
        const float* as = &As[p][0];
        const float* bs = &Bs[p][0];
        #pragma unroll
        for (int k = 0; k < KC; ++k) {
            const float4 a0 = *(const float4*)(as + k * LDSS + tm);
            const float4 a1 = *(const float4*)(as + k * LDSS + tm + 64);
            const float4 b0 = *(const float4*)(bs + k * LDSS + tn);
            const float4 b1 = *(const float4*)(bs + k * LDSS + tn + 64);
            const float a[8] = {a0.x, a0.y, a0.z, a0.w, a1.x, a1.y, a1.z, a1.w};
            const float b[8] = {b0.x, b0.y, b0.z, b0.w, b1.x, b1.y, b1.z, b1.w};
            #pragma unroll
            for (int i = 0; i < 8; ++i)
                #pragma unroll
                for (int j = 0; j < 8; ++j)
                    acc[i][j] += a[i] * b[j];
        }
        if (has_next) {
            float* asn = &As[1 ^ p][0];
            float* bsn = &Bs[1 ^ p][0];
            asn[(sk + 0) * LDSS + srow] = av0.x;  asn[(sk + 1) * LDSS + srow] = av0.y;
            asn[(sk + 2) * LDSS + srow] = av0.z;  asn[(sk + 3) * LDSS + srow] = av0.w;
            asn[(sk + 0) * LDSS + srow + 64] = av1.x;  asn[(sk + 1) * LDSS + srow + 64] = av1.y;
            asn[(sk + 2) * LDSS + srow + 64] = av1.z;  asn[(sk + 3) * LDSS + srow + 64] = av1.w;
            bsn[(sk + 0) * LDSS + srow] = bv0.x;  bsn[(sk + 1) * LDSS + srow] = bv0.y;
            bsn[(sk + 2) * LDSS + srow] = bv0.z;  bsn[(sk + 3) * LDSS + srow] = bv0.w;
            bsn[(sk + 0) * LDSS + srow + 64] = bv1.x;  bsn[(sk + 1) * LDSS + srow + 64] = bv1.y;
            bsn[(sk + 2) * LDSS + srow + 64] = bv1.z;  bsn[(sk + 3) * LDSS + srow + 64] = bv1.w;
        }
        __syncthreads();
        p ^= 1;
    }

    #pragma unroll
    for (int i = 0; i < 8; ++i) {
        const int m = m0 + ((i < 4) ? (tm + i) : (tm + 60 + i));  // tm+64+(i-4)
        const float4 c0 = make_float4(acc[i][0], acc[i][1], acc[i][2], acc[i][3]);
        const float4 c1 = make_float4(acc[i][4], acc[i][5], acc[i][6], acc[i][7]);
        *(float4*)(C + (size_t)m * F_DIM + n0 + tn) = c0;
        *(float4*)(C + (size_t)m * F_DIM + n0 + tn + 64) = c1;
    }
}

// ---------------- sequential LIF scan over a chunk of Tc steps ----------------
// Depth-16 register ring buffer: loads are independent of the serial compute
// chain, so ~16 wave-loads stay in flight (latency-bound -> BW-bound).
// Explicit _rn intrinsics: forbid fma contraction (matches reference rounding).
#define DEPTH 16

__global__ __launch_bounds__(256)
void scan_kernel(const float* __restrict__ xs, float* __restrict__ vi,
                 float* __restrict__ out, int Tc, int first, int last) {
    const int j = blockIdx.x * 256 + threadIdx.x;  // neuron id, 0..NB-1
    float v, cur;
    if (first) { v = 0.f; cur = 0.f; }
    else       { v = vi[j]; cur = vi[NB + j]; }
    float z = 0.f;
    const float* pj = xs + j;

    if (Tc >= DEPTH && (Tc % DEPTH) == 0) {
        float buf[DEPTH];
        #pragma unroll
        for (int d = 0; d < DEPTH; ++d) buf[d] = pj[(size_t)d * NB];
        for (int tt = 0; tt < Tc; tt += DEPTH) {
            #pragma unroll
            for (int d = 0; d < DEPTH; ++d) {
                const float x = buf[d];
                int tn = tt + DEPTH + d;
                tn = (tn < Tc) ? tn : 0;          // clamped dead prefetch at tail
                buf[d] = pj[(size_t)tn * NB];
                const float vd = __fadd_rn(v, __fmul_rn(0.1f, __fsub_rn(cur, v)));
                const float id = __fadd_rn(cur, __fmul_rn(-0.2f, cur));
                const bool sp = vd > 1.0f;
                z = sp ? 1.f : 0.f;
                v = sp ? 0.f : vd;
                cur = __fadd_rn(id, x);
            }
        }
    } else {
        for (int t = 0; t < Tc; ++t) {
            const float x = pj[(size_t)t * NB];
            const float vd = __fadd_rn(v, __fmul_rn(0.1f, __fsub_rn(cur, v)));
            const float id = __fadd_rn(cur, __fmul_rn(-0.2f, cur));
            const bool sp = vd > 1.0f;
            z = sp ? 1.f : 0.f;
            v = sp ? 0.f : vd;
            cur = __fadd_rn(id, x);
        }
    }

    if (last) {
        out[j]           = z;
        out[NB + j]      = z;
        out[2 * NB + j]  = v;
        out[3 * NB + j]  = cur;
    } else {
        vi[j]      = v;
        vi[NB + j] = cur;
    }
}

extern "C" void kernel_launch(void* const* d_in, const int* in_sizes, int n_in,
                              void* d_out, int out_size, void* d_ws, size_t ws_size,
                              hipStream_t stream) {
    const float* S = (const float*)d_in[0];  // [T,B,F] fp32
    const float* W = (const float*)d_in[1];  // [F,F] fp32
    float* out = (float*)d_out;
    float* vi = (float*)d_ws;        // 2*NB floats of state
    float* xs = vi + 2 * NB;         // chunk buffer [Tc, NB]
    // pick largest power-of-two chunk Tc whose xs buffer fits the workspace
    const size_t avail_f = (ws_size / 4 > (size_t)(2 * NB)) ? ws_size / 4 - 2 * NB : 0;
    int Tc = T_DIM;
    while (Tc > 1 && (size_t)Tc * NB > avail_f) Tc >>= 1;
    const int nc = T_DIM / Tc;
    for (int c = 0; c < nc; ++c) {
        const int M = Tc * B_DIM;
        dim3 grid(M / TM, F_DIM / TN);
        gemm_kernel<<<grid, 256, 0, stream>>>(S + (size_t)c * Tc * NB, W, xs);
        scan_kernel<<<NB / 256, 256, 0, stream>>>(xs, vi, out, Tc,
                                                  (c == 0) ? 1 : 0,
                                                  (c == nc - 1) ? 1 : 0);
    }
}

// Round 3
// 1244.026 us; speedup vs baseline: 11.7527x; 11.7527x over previous
//
#include <hip/hip_runtime.h>

// LIF benchmark: xs = einsum('tbf,gf->tbg', S, W)  (fp32 GEMM, A=S [T*B,512], B=W [512,512], NT)
// then sequential scan over T with per-neuron (v,i) state and heaviside threshold.
// Outputs: [z_final, z_final, v_final, i_final], each [128,512] fp32.
//
// R3: launch_bounds(256,2) — (256,4) capped regs at 128/wave and spilled acc to
// scratch (36 GB writes). 8x16 micro-tile raises FLOPs/LDS-byte (R0 was bound by
// ds_read_b128 ~85 B/cy, not VALU). Per-element FMA chain stays ascending-k,
// bit-identical to R0 (absmax 0.0).

#define T_DIM 1024
#define B_DIM 128
#define F_DIM 512
#define NB (B_DIM * F_DIM)  // 65536 neurons

// ---------------- GEMM: C[m][n] = sum_k A[m][k] * W[n][k] ----------------
// Block tile 128m x 256n, 256 threads, 8x16 micro-tile, KC=16, double-buffered.
#define TM 128
#define TN 256
#define KC 16
#define LDA_S 132  // As row pad: bank = (4k'+m)%32 -> 2-way on stores (free)
#define LDB_S 260  // Bs row pad

__global__ __launch_bounds__(256, 2)
void gemm_kernel(const float* __restrict__ A, const float* __restrict__ W,
                 float* __restrict__ C) {
    __shared__ float As[2][KC * LDA_S];  // [k][m]
    __shared__ float Bs[2][KC * LDB_S];  // [k][n]
    const int tid = threadIdx.x;
    const int m0 = blockIdx.x * TM;
    const int n0 = blockIdx.y * TN;
    const int tn4 = (tid & 15) * 4;  // b cols: tn4 + {0..3} + 64q, q=0..3
    const int tm4 = (tid >> 4) * 4;  // a rows: tm4 + {0..3} and +64
    const int srow = tid >> 2;       // staging row 0..63 (+64p)
    const int sk = (tid & 3) * 4;    // staging k 0,4,8,12

    const float* Ag = A + (size_t)(m0 + srow) * F_DIM + sk;
    const float* Wg = W + (size_t)(n0 + srow) * F_DIM + sk;

    float acc[8][16];
    #pragma unroll
    for (int i = 0; i < 8; ++i)
        #pragma unroll
        for (int j = 0; j < 16; ++j) acc[i][j] = 0.f;

    float4 apf[2], bpf[4];
    // preload tile 0
    #pragma unroll
    for (int p = 0; p < 2; ++p) apf[p] = *(const float4*)(Ag + (size_t)(64 * p) * F_DIM);
    #pragma unroll
    for (int p = 0; p < 4; ++p) bpf[p] = *(const float4*)(Wg + (size_t)(64 * p) * F_DIM);
    {
        float* as = &As[0][0];
        float* bs = &Bs[0][0];
        #pragma unroll
        for (int p = 0; p < 2; ++p) {
            const int r = srow + 64 * p;
            as[(sk + 0) * LDA_S + r] = apf[p].x;  as[(sk + 1) * LDA_S + r] = apf[p].y;
            as[(sk + 2) * LDA_S + r] = apf[p].z;  as[(sk + 3) * LDA_S + r] = apf[p].w;
        }
        #pragma unroll
        for (int p = 0; p < 4; ++p) {
            const int r = srow + 64 * p;
            bs[(sk + 0) * LDB_S + r] = bpf[p].x;  bs[(sk + 1) * LDB_S + r] = bpf[p].y;
            bs[(sk + 2) * LDB_S + r] = bpf[p].z;  bs[(sk + 3) * LDB_S + r] = bpf[p].w;
        }
    }
    __syncthreads();

    int pb = 0;
    for (int k0 = 0; k0 < F_DIM; k0 += KC) {
        const bool has_next = (k0 + KC < F_DIM);
        if (has_next) {
            #pragma unroll
            for (int p = 0; p < 2; ++p)
                apf[p] = *(const float4*)(Ag + k0 + KC + (size_t)(64 * p) * F_DIM);
            #pragma unroll
            for (int p = 0; p < 4; ++p)
                bpf[p] = *(const float4*)(Wg + k0 + KC + (size_t)(64 * p) * F_DIM);
        }
        const float* as = &As[pb][0];
        const float* bs = &Bs[pb][0];
        #pragma unroll 4
        for (int k = 0; k < KC; ++k) {
            const float4 a0 = *(const float4*)(as + k * LDA_S + tm4);
            const float4 a1 = *(const float4*)(as + k * LDA_S + tm4 + 64);
            const float4 b0 = *(const float4*)(bs + k * LDB_S + tn4);
            const float4 b1 = *(const float4*)(bs + k * LDB_S + tn4 + 64);
            const float4 b2 = *(const float4*)(bs + k * LDB_S + tn4 + 128);
            const float4 b3 = *(const float4*)(bs + k * LDB_S + tn4 + 192);
            const float a[8] = {a0.x, a0.y, a0.z, a0.w, a1.x, a1.y, a1.z, a1.w};
            const float b[16] = {b0.x, b0.y, b0.z, b0.w, b1.x, b1.y, b1.z, b1.w,
                                 b2.x, b2.y, b2.z, b2.w, b3.x, b3.y, b3.z, b3.w};
            #pragma unroll
            for (int i = 0; i < 8; ++i)
                #pragma unroll
                for (int j = 0; j < 16; ++j)
                    acc[i][j] += a[i] * b[j];
        }
        if (has_next) {
            float* asn = &As[1 ^ pb][0];
            float* bsn = &Bs[1 ^ pb][0];
            #pragma unroll
            for (int p = 0; p < 2; ++p) {
                const int r = srow + 64 * p;
                asn[(sk + 0) * LDA_S + r] = apf[p].x;  asn[(sk + 1) * LDA_S + r] = apf[p].y;
                asn[(sk + 2) * LDA_S + r] = apf[p].z;  asn[(sk + 3) * LDA_S + r] = apf[p].w;
            }
            #pragma unroll
            for (int p = 0; p < 4; ++p) {
                const int r = srow + 64 * p;
                bsn[(sk + 0) * LDB_S + r] = bpf[p].x;  bsn[(sk + 1) * LDB_S + r] = bpf[p].y;
                bsn[(sk + 2) * LDB_S + r] = bpf[p].z;  bsn[(sk + 3) * LDB_S + r] = bpf[p].w;
            }
        }
        __syncthreads();
        pb ^= 1;
    }

    #pragma unroll
    for (int i = 0; i < 8; ++i) {
        const int m = m0 + ((i < 4) ? (tm4 + i) : (tm4 + 60 + i));  // tm4+64+(i-4)
        #pragma unroll
        for (int q = 0; q < 4; ++q) {
            const float4 c = make_float4(acc[i][4 * q + 0], acc[i][4 * q + 1],
                                         acc[i][4 * q + 2], acc[i][4 * q + 3]);
            *(float4*)(C + (size_t)m * F_DIM + n0 + tn4 + 64 * q) = c;
        }
    }
}

// ---------------- sequential LIF scan over a chunk of Tc steps ----------------
// Depth-32 register ring buffer keeps ~32 KB/CU of loads in flight.
// Explicit _rn intrinsics: forbid fma contraction (matches reference rounding).
#define DEPTH 32

__global__ __launch_bounds__(256)
void scan_kernel(const float* __restrict__ xs, float* __restrict__ vi,
                 float* __restrict__ out, int Tc, int first, int last) {
    const int j = blockIdx.x * 256 + threadIdx.x;  // neuron id, 0..NB-1
    float v, cur;
    if (first) { v = 0.f; cur = 0.f; }
    else       { v = vi[j]; cur = vi[NB + j]; }
    float z = 0.f;
    const float* pj = xs + j;

    if (Tc >= DEPTH && (Tc % DEPTH) == 0) {
        float buf[DEPTH];
        #pragma unroll
        for (int d = 0; d < DEPTH; ++d) buf[d] = pj[(size_t)d * NB];
        for (int tt = 0; tt < Tc; tt += DEPTH) {
            #pragma unroll
            for (int d = 0; d < DEPTH; ++d) {
                const float x = buf[d];
                int tn = tt + DEPTH + d;
                tn = (tn < Tc) ? tn : 0;          // clamped dead prefetch at tail
                buf[d] = pj[(size_t)tn * NB];
                const float vd = __fadd_rn(v, __fmul_rn(0.1f, __fsub_rn(cur, v)));
                const float id = __fadd_rn(cur, __fmul_rn(-0.2f, cur));
                const bool sp = vd > 1.0f;
                z = sp ? 1.f : 0.f;
                v = sp ? 0.f : vd;
                cur = __fadd_rn(id, x);
            }
        }
    } else {
        for (int t = 0; t < Tc; ++t) {
            const float x = pj[(size_t)t * NB];
            const float vd = __fadd_rn(v, __fmul_rn(0.1f, __fsub_rn(cur, v)));
            const float id = __fadd_rn(cur, __fmul_rn(-0.2f, cur));
            const bool sp = vd > 1.0f;
            z = sp ? 1.f : 0.f;
            v = sp ? 0.f : vd;
            cur = __fadd_rn(id, x);
        }
    }

    if (last) {
        out[j]           = z;
        out[NB + j]      = z;
        out[2 * NB + j]  = v;
        out[3 * NB + j]  = cur;
    } else {
        vi[j]      = v;
        vi[NB + j] = cur;
    }
}

extern "C" void kernel_launch(void* const* d_in, const int* in_sizes, int n_in,
                              void* d_out, int out_size, void* d_ws, size_t ws_size,
                              hipStream_t stream) {
    const float* S = (const float*)d_in[0];  // [T,B,F] fp32
    const float* W = (const float*)d_in[1];  // [F,F] fp32
    float* out = (float*)d_out;
    float* vi = (float*)d_ws;        // 2*NB floats of state
    float* xs = vi + 2 * NB;         // chunk buffer [Tc, NB]
    // pick largest power-of-two chunk Tc whose xs buffer fits the workspace
    const size_t avail_f = (ws_size / 4 > (size_t)(2 * NB)) ? ws_size / 4 - 2 * NB : 0;
    int Tc = T_DIM;
    while (Tc > 1 && (size_t)Tc * NB > avail_f) Tc >>= 1;
    const int nc = T_DIM / Tc;
    for (int c = 0; c < nc; ++c) {
        const int M = Tc * B_DIM;
        dim3 grid(M / TM, F_DIM / TN);
        gemm_kernel<<<grid, 256, 0, stream>>>(S + (size_t)c * Tc * NB, W, xs);
        scan_kernel<<<NB / 256, 256, 0, stream>>>(xs, vi, out, Tc,
                                                  (c == 0) ? 1 : 0,
                                                  (c == nc - 1) ? 1 : 0);
    }
}

// Round 5
// 1088.651 us; speedup vs baseline: 13.4301x; 1.1427x over previous
//
#include <hip/hip_runtime.h>

// LIF benchmark: xs = einsum('tbf,gf->tbg', S, W)  (fp32 GEMM, A=S [T*B,512], B=W [512,512], NT)
// then sequential scan over T with per-neuron (v,i) state and heaviside threshold.
// Outputs: [z_final, z_final, v_final, i_final], each [128,512] fp32.
//
// R5: recomposed ONLY from proven-passed pieces after R4's silent failure
// (stub-identical signature -> R4's novel gemm/scan structures untrusted).
//   - GEMM: R0's single-buffer skeleton + R0 staging geometry (srow=tid>>3,
//     sk=(tid&7)*4, KC=32; passed bit-exact twice), with R3's proven 8x16
//     compute loop + epilogue (passed bit-exact) and TN=256 (B staged with the
//     same R0 pattern, 8 pages). 8x16 raises FLOP/LDS-byte: per wave-k,
//     LDS 6xb128=72cy vs FMA 128instr=64cy (R0's 8x8 was LDS-bound 48vs32).
//   - Scan: verbatim R3 ring scan (passed, ~200us).
// All FMA chains ascending-k, fused (matches np/BLAS ascending-k fma chains ->
// absmax 0.0 in R0/R1/R3).

#define T_DIM 1024
#define B_DIM 128
#define F_DIM 512
#define NB (B_DIM * F_DIM)  // 65536 neurons

// ---------------- GEMM: C[m][n] = sum_k A[m][k] * W[n][k] ----------------
// Block tile 128m x 256n, 256 threads, 8x16 micro-tile, KC=32, single-buffered.
#define TM 128
#define TN 256
#define KC 32
#define LDA_S 132  // As row pad
#define LDB_S 260  // Bs row pad

__global__ __launch_bounds__(256, 2)
void gemm_kernel(const float* __restrict__ A, const float* __restrict__ W,
                 float* __restrict__ C) {
    __shared__ float As[KC * LDA_S];  // [k][m]
    __shared__ float Bs[KC * LDB_S];  // [k][n]
    const int tid = threadIdx.x;
    const int m0 = blockIdx.x * TM;
    const int n0 = blockIdx.y * TN;
    const int tn4 = (tid & 15) * 4;  // b cols: tn4 + {0..3} + 64q, q=0..3
    const int tm4 = (tid >> 4) * 4;  // a rows: tm4 + {0..3} and +64
    const int srow = tid >> 3;       // staging row 0..31 (+32p)  [R0 geometry]
    const int sk = (tid & 7) * 4;    // staging k 0,4,...,28      [R0 geometry]

    float acc[8][16];
    #pragma unroll
    for (int i = 0; i < 8; ++i)
        #pragma unroll
        for (int j = 0; j < 16; ++j) acc[i][j] = 0.f;

    for (int k0 = 0; k0 < F_DIM; k0 += KC) {
        // global loads for this tile (regs die at the LDS stores)
        float4 av[4], bv[8];
        #pragma unroll
        for (int p = 0; p < 4; ++p)
            av[p] = *(const float4*)(A + (size_t)(m0 + srow + 32 * p) * F_DIM + k0 + sk);
        #pragma unroll
        for (int p = 0; p < 8; ++p)
            bv[p] = *(const float4*)(W + (size_t)(n0 + srow + 32 * p) * F_DIM + k0 + sk);
        __syncthreads();  // previous tile's compute done before overwrite
        #pragma unroll
        for (int p = 0; p < 4; ++p) {
            const int r = srow + 32 * p;
            As[(sk + 0) * LDA_S + r] = av[p].x;  As[(sk + 1) * LDA_S + r] = av[p].y;
            As[(sk + 2) * LDA_S + r] = av[p].z;  As[(sk + 3) * LDA_S + r] = av[p].w;
        }
        #pragma unroll
        for (int p = 0; p < 8; ++p) {
            const int r = srow + 32 * p;
            Bs[(sk + 0) * LDB_S + r] = bv[p].x;  Bs[(sk + 1) * LDB_S + r] = bv[p].y;
            Bs[(sk + 2) * LDB_S + r] = bv[p].z;  Bs[(sk + 3) * LDB_S + r] = bv[p].w;
        }
        __syncthreads();

        #pragma unroll 4
        for (int k = 0; k < KC; ++k) {
            const float4 a0 = *(const float4*)(As + k * LDA_S + tm4);
            const float4 a1 = *(const float4*)(As + k * LDA_S + tm4 + 64);
            const float4 b0 = *(const float4*)(Bs + k * LDB_S + tn4);
            const float4 b1 = *(const float4*)(Bs + k * LDB_S + tn4 + 64);
            const float4 b2 = *(const float4*)(Bs + k * LDB_S + tn4 + 128);
            const float4 b3 = *(const float4*)(Bs + k * LDB_S + tn4 + 192);
            const float a[8] = {a0.x, a0.y, a0.z, a0.w, a1.x, a1.y, a1.z, a1.w};
            const float b[16] = {b0.x, b0.y, b0.z, b0.w, b1.x, b1.y, b1.z, b1.w,
                                 b2.x, b2.y, b2.z, b2.w, b3.x, b3.y, b3.z, b3.w};
            #pragma unroll
            for (int i = 0; i < 8; ++i)
                #pragma unroll
                for (int j = 0; j < 16; ++j)
                    acc[i][j] += a[i] * b[j];
        }
    }

    #pragma unroll
    for (int i = 0; i < 8; ++i) {
        const int m = m0 + ((i < 4) ? (tm4 + i) : (tm4 + 60 + i));  // tm4+64+(i-4)
        #pragma unroll
        for (int q = 0; q < 4; ++q) {
            const float4 c = make_float4(acc[i][4 * q + 0], acc[i][4 * q + 1],
                                         acc[i][4 * q + 2], acc[i][4 * q + 3]);
            *(float4*)(C + (size_t)m * F_DIM + n0 + tn4 + 64 * q) = c;
        }
    }
}

// ---------------- sequential LIF scan over a chunk of Tc steps ----------------
// Verbatim R3 (passed): depth-32 register ring buffer.
// Explicit _rn intrinsics: forbid fma contraction (matches reference rounding).
#define DEPTH 32

__global__ __launch_bounds__(256)
void scan_kernel(const float* __restrict__ xs, float* __restrict__ vi,
                 float* __restrict__ out, int Tc, int first, int last) {
    const int j = blockIdx.x * 256 + threadIdx.x;  // neuron id, 0..NB-1
    float v, cur;
    if (first) { v = 0.f; cur = 0.f; }
    else       { v = vi[j]; cur = vi[NB + j]; }
    float z = 0.f;
    const float* pj = xs + j;

    if (Tc >= DEPTH && (Tc % DEPTH) == 0) {
        float buf[DEPTH];
        #pragma unroll
        for (int d = 0; d < DEPTH; ++d) buf[d] = pj[(size_t)d * NB];
        for (int tt = 0; tt < Tc; tt += DEPTH) {
            #pragma unroll
            for (int d = 0; d < DEPTH; ++d) {
                const float x = buf[d];
                int tn = tt + DEPTH + d;
                tn = (tn < Tc) ? tn : 0;          // clamped dead prefetch at tail
                buf[d] = pj[(size_t)tn * NB];
                const float vd = __fadd_rn(v, __fmul_rn(0.1f, __fsub_rn(cur, v)));
                const float id = __fadd_rn(cur, __fmul_rn(-0.2f, cur));
                const bool sp = vd > 1.0f;
                z = sp ? 1.f : 0.f;
                v = sp ? 0.f : vd;
                cur = __fadd_rn(id, x);
            }
        }
    } else {
        for (int t = 0; t < Tc; ++t) {
            const float x = pj[(size_t)t * NB];
            const float vd = __fadd_rn(v, __fmul_rn(0.1f, __fsub_rn(cur, v)));
            const float id = __fadd_rn(cur, __fmul_rn(-0.2f, cur));
            const bool sp = vd > 1.0f;
            z = sp ? 1.f : 0.f;
            v = sp ? 0.f : vd;
            cur = __fadd_rn(id, x);
        }
    }

    if (last) {
        out[j]           = z;
        out[NB + j]      = z;
        out[2 * NB + j]  = v;
        out[3 * NB + j]  = cur;
    } else {
        vi[j]      = v;
        vi[NB + j] = cur;
    }
}

extern "C" void kernel_launch(void* const* d_in, const int* in_sizes, int n_in,
                              void* d_out, int out_size, void* d_ws, size_t ws_size,
                              hipStream_t stream) {
    const float* S = (const float*)d_in[0];  // [T,B,F] fp32
    const float* W = (const float*)d_in[1];  // [F,F] fp32
    float* out = (float*)d_out;
    float* vi = (float*)d_ws;        // 2*NB floats of state
    float* xs = vi + 2 * NB;         // chunk buffer [Tc, NB]
    // pick largest power-of-two chunk Tc whose xs buffer fits the workspace
    const size_t avail_f = (ws_size / 4 > (size_t)(2 * NB)) ? ws_size / 4 - 2 * NB : 0;
    int Tc = T_DIM;
    while (Tc > 1 && (size_t)Tc * NB > avail_f) Tc >>= 1;
    const int nc = T_DIM / Tc;
    for (int c = 0; c < nc; ++c) {
        const int M = Tc * B_DIM;
        dim3 grid(M / TM, F_DIM / TN);
        gemm_kernel<<<grid, 256, 0, stream>>>(S + (size_t)c * Tc * NB, W, xs);
        scan_kernel<<<NB / 256, 256, 0, stream>>>(xs, vi, out, Tc,
                                                  (c == 0) ? 1 : 0,
                                                  (c == nc - 1) ? 1 : 0);
    }
}